// Round 1
// baseline (2526.249 us; speedup 1.0000x reference)
//
#include <hip/hip_runtime.h>
#include <math.h>

#define BT 65536      // batch rows
#define NIN 1024      // input dim (reduction)
#define KK 1024       // codes (logit cols)
#define EE 256        // embedding dim
#define MT 32         // rows per block
#define NB 256        // cols per col-block
#define NCB 4         // col-blocks (NB*NCB = KK)
#define KB 32         // reduction chunk
#define XS 36         // xs LDS row stride (padded)
#define WS 260        // ws LDS row stride (padded)
#define LOGK 6.9314718055994531f

// Main fused kernel: logits GEMM + gumbel + softmax stats + argmax + codebook
// gather + avg_p partial accumulation.
// Block: 256 threads = 8 row-groups (tr) x 32 col-threads (tc).
// Thread tile: 4 rows x 8 cols per col-block; logits live in registers
// (lg[4][32] = 128 VGPRs) across all 4 col-blocks.
__global__ __launch_bounds__(256, 2)
void vq_main(const float* __restrict__ x, const float* __restrict__ gum,
             const float* __restrict__ W, const float* __restrict__ bias,
             const float* __restrict__ cbk, float* __restrict__ out,
             float* __restrict__ gsum) {
    __shared__ float smem[XS * KB + WS * KB];   // 37.9 KB
    float* xs = smem;            // [n][row]  KB x XS
    float* ws = smem + XS * KB;  // [n][col]  KB x WS

    const int tid = threadIdx.x;
    const int tc = tid & 31;          // 0..31 -> cols 8*tc..8*tc+7 within col-block
    const int tr = tid >> 5;          // 0..7  -> rows 4*tr..4*tr+3
    const int row0 = blockIdx.x * MT;

    float lg[4][32];                  // [row i][cb*8+j]
    #pragma unroll
    for (int i = 0; i < 4; ++i)
        #pragma unroll
        for (int t = 0; t < 32; ++t) lg[i][t] = 0.f;

    const int xrow = tid >> 3;          // 0..31
    const int xn   = (tid & 7) << 2;    // 0,4,...,28

    for (int kc = 0; kc < NIN / KB; ++kc) {
        const int n0 = kc * KB;
        // stage x tile (32 rows x 32 n), transposed into xs[n][row]
        const float4 xv = *(const float4*)(x + (size_t)(row0 + xrow) * NIN + n0 + xn);
        xs[(xn + 0) * XS + xrow] = xv.x;
        xs[(xn + 1) * XS + xrow] = xv.y;
        xs[(xn + 2) * XS + xrow] = xv.z;
        xs[(xn + 3) * XS + xrow] = xv.w;

        #pragma unroll
        for (int cb = 0; cb < NCB; ++cb) {
            // stage W tile (256 cols x 32 n), transposed into ws[n][col]
            #pragma unroll
            for (int l = 0; l < 8; ++l) {
                const int flat = tid + l * 256;
                const int wn = (flat & 7) << 2;   // 0..28
                const int wc = flat >> 3;         // 0..255
                const float4 wv = *(const float4*)(W + (size_t)(cb * NB + wc) * NIN + n0 + wn);
                ws[(wn + 0) * WS + wc] = wv.x;
                ws[(wn + 1) * WS + wc] = wv.y;
                ws[(wn + 2) * WS + wc] = wv.z;
                ws[(wn + 3) * WS + wc] = wv.w;
            }
            __syncthreads();
            #pragma unroll
            for (int n = 0; n < KB; ++n) {
                const float4 a  = *(const float4*)(xs + n * XS + 4 * tr);
                const float4 b0 = *(const float4*)(ws + n * WS + 8 * tc);
                const float4 b1 = *(const float4*)(ws + n * WS + 8 * tc + 4);
                const float av[4] = {a.x, a.y, a.z, a.w};
                const float bv[8] = {b0.x, b0.y, b0.z, b0.w, b1.x, b1.y, b1.z, b1.w};
                #pragma unroll
                for (int i = 0; i < 4; ++i)
                    #pragma unroll
                    for (int j = 0; j < 8; ++j)
                        lg[i][cb * 8 + j] = fmaf(av[i], bv[j], lg[i][cb * 8 + j]);
            }
            __syncthreads();
        }
    }

    // add bias + gumbel (tau = 1.0)
    #pragma unroll
    for (int cb = 0; cb < NCB; ++cb) {
        const int cbase = cb * NB + 8 * tc;
        const float4 bb0 = *(const float4*)(bias + cbase);
        const float4 bb1 = *(const float4*)(bias + cbase + 4);
        #pragma unroll
        for (int i = 0; i < 4; ++i) {
            const int row = row0 + 4 * tr + i;
            const float4 g0 = *(const float4*)(gum + (size_t)row * KK + cbase);
            const float4 g1 = *(const float4*)(gum + (size_t)row * KK + cbase + 4);
            lg[i][cb * 8 + 0] += bb0.x + g0.x;
            lg[i][cb * 8 + 1] += bb0.y + g0.y;
            lg[i][cb * 8 + 2] += bb0.z + g0.z;
            lg[i][cb * 8 + 3] += bb0.w + g0.w;
            lg[i][cb * 8 + 4] += bb1.x + g1.x;
            lg[i][cb * 8 + 5] += bb1.y + g1.y;
            lg[i][cb * 8 + 6] += bb1.z + g1.z;
            lg[i][cb * 8 + 7] += bb1.w + g1.w;
        }
    }

    // per-row: argmax (first-occurrence tie-break), softmax, z_q gather, m
    #pragma unroll
    for (int i = 0; i < 4; ++i) {
        float mv = -1e30f; int mi = 0;
        #pragma unroll
        for (int t = 0; t < 32; ++t) {
            const int c = (t >> 3) * NB + 8 * tc + (t & 7);
            if (lg[i][t] > mv) { mv = lg[i][t]; mi = c; }
        }
        // reduce across the 32 lanes sharing this row-group (xor masks < 32
        // keep the half-wave group intact)
        #pragma unroll
        for (int off = 1; off < 32; off <<= 1) {
            const float ov = __shfl_xor(mv, off);
            const int   oi = __shfl_xor(mi, off);
            if (ov > mv || (ov == mv && oi < mi)) { mv = ov; mi = oi; }
        }
        float s = 0.f;
        #pragma unroll
        for (int t = 0; t < 32; ++t) {
            const float e = __expf(lg[i][t] - mv);
            lg[i][t] = e;
            s += e;
        }
        #pragma unroll
        for (int off = 1; off < 32; off <<= 1) s += __shfl_xor(s, off);
        const float rinv = 1.f / s;
        #pragma unroll
        for (int t = 0; t < 32; ++t) lg[i][t] *= rinv;

        const int row = row0 + 4 * tr + i;
        // z_q[row] = codebook[mi]  (forward value of straight-through = hard)
        const float4 c0 = *(const float4*)(cbk + (size_t)mi * EE + 8 * tc);
        const float4 c1 = *(const float4*)(cbk + (size_t)mi * EE + 8 * tc + 4);
        *(float4*)(out + (size_t)row * EE + 8 * tc)     = c0;
        *(float4*)(out + (size_t)row * EE + 8 * tc + 4) = c1;
        if (tc == 0) out[(size_t)BT * EE + row] = (float)mi;
    }

    // avg_p partials: sum p over this block's 32 rows per column, then one
    // global atomicAdd per column per block.
    #pragma unroll
    for (int t = 0; t < 32; ++t) lg[0][t] += lg[1][t] + lg[2][t] + lg[3][t];
    __syncthreads();                 // done with GEMM staging; reuse smem
    float* aggp = smem;
    for (int q = tid; q < KK; q += 256) aggp[q] = 0.f;
    __syncthreads();
    #pragma unroll
    for (int t = 0; t < 32; ++t)
        atomicAdd(&aggp[(t >> 3) * NB + 8 * tc + (t & 7)], lg[0][t]);
    __syncthreads();
    for (int q = tid; q < KK; q += 256) atomicAdd(&gsum[q], aggp[q]);
}

// Finalize: diversity = sum avg_p * (log(clip(avg_p,1e-9)) + log K); also the
// trailing zero scalar.
__global__ void vq_fin(const float* __restrict__ gsum, float* __restrict__ out) {
    __shared__ float red[4];
    const int tid = threadIdx.x;
    float local = 0.f;
    for (int q = tid; q < KK; q += 256) {
        const float a = gsum[q] * (1.0f / (float)BT);
        local += a * (logf(fmaxf(a, 1e-9f)) + LOGK);
    }
    #pragma unroll
    for (int off = 1; off < 64; off <<= 1) local += __shfl_xor(local, off);
    if ((tid & 63) == 0) red[tid >> 6] = local;
    __syncthreads();
    if (tid == 0) {
        out[(size_t)BT * EE + BT]     = red[0] + red[1] + red[2] + red[3];
        out[(size_t)BT * EE + BT + 1] = 0.f;
    }
}

extern "C" void kernel_launch(void* const* d_in, const int* in_sizes, int n_in,
                              void* d_out, int out_size, void* d_ws, size_t ws_size,
                              hipStream_t stream) {
    const float* x   = (const float*)d_in[0];
    const float* g   = (const float*)d_in[1];
    const float* W   = (const float*)d_in[2];
    const float* b   = (const float*)d_in[3];
    const float* cbk = (const float*)d_in[4];
    float* out  = (float*)d_out;
    float* gsum = (float*)d_ws;

    hipMemsetAsync(gsum, 0, KK * sizeof(float), stream);
    vq_main<<<BT / MT, 256, 0, stream>>>(x, g, W, b, cbk, out, gsum);
    vq_fin<<<1, 256, 0, stream>>>(gsum, out);
}